// Round 6
// baseline (411.404 us; speedup 1.0000x reference)
//
#include <hip/hip_runtime.h>
#include <hip/hip_bf16.h>
#include <stdint.h>

namespace {

typedef __attribute__((ext_vector_type(8))) short s8v;
typedef __attribute__((ext_vector_type(4))) short s4v;
typedef __attribute__((ext_vector_type(4))) float f4v;
typedef __attribute__((ext_vector_type(8))) unsigned short us8;

constexpr int kN = 343;                        // window tokens (7^3)
constexpr size_t kPlaneE = 768ull * 343 * 32;  // elems per q/k/v plane
constexpr int kM = 21952;                      // real rows
constexpr float kL2E = 1.44269504f;

__device__ __forceinline__ int regionOf(int c) { return c < 7 ? 0 : (c < 11 ? 1 : 2); }

__device__ __forceinline__ int winRowMap(int wtok) {
  int w = wtok / kN, nn = wtok % kN;
  int bb = w >> 3, nwi = w & 7;
  int nz = nn / 49, nh = (nn / 7) % 7, nw = nn % 7;
  int uz = (((nwi >> 2) & 1) * 7 + nz + 3) % 14;
  int uh = (((nwi >> 1) & 1) * 7 + nh + 3) % 14;
  int uw = (((nwi     ) & 1) * 7 + nw + 3) % 14;
  return bb * 2744 + uz * 196 + uh * 14 + uw;
}

__device__ __forceinline__ unsigned short f2bf(float f) {
  union { float f; unsigned u; } a; a.f = f;
  unsigned r = a.u + 0x7fffu + ((a.u >> 16) & 1u);
  return (unsigned short)(r >> 16);
}
__device__ __forceinline__ float bf2f(unsigned short u) {
  union { unsigned u; float f; } a; a.u = ((unsigned)u) << 16; return a.f;
}
__device__ __forceinline__ unsigned cvtpk(float lo, float hi) {
  unsigned r;
  asm("v_cvt_pk_bf16_f32 %0, %1, %2" : "=v"(r) : "v"(lo), "v"(hi));
  return r;
}
__device__ __forceinline__ float fexp2(float x) {
#if __has_builtin(__builtin_amdgcn_exp2f)
  return __builtin_amdgcn_exp2f(x);
#else
  return exp2f(x);
#endif
}

#if __has_builtin(__builtin_amdgcn_mfma_f32_16x16x16bf16_1k)
__device__ __forceinline__ f4v mfma16(s4v a, s4v b, f4v c) {
  return __builtin_amdgcn_mfma_f32_16x16x16bf16_1k(a, b, c, 0, 0, 0);
}
#else
__device__ __forceinline__ f4v mfma16(s4v a, s4v b, f4v c) {
  f4v d;
  asm("v_mfma_f32_16x16x16_bf16 %0, %1, %2, %3" : "=v"(d) : "v"(a), "v"(b), "v"(c));
  return d;
}
#endif

__device__ __forceinline__ void gload16(const void* g, void* l) {
  __builtin_amdgcn_global_load_lds(
      (const __attribute__((address_space(1))) unsigned int*)g,
      (__attribute__((address_space(3))) unsigned int*)l, 16, 0, 0);
}

__device__ __forceinline__ float cpbFeat(int i) {
  float v = (float)(i - 6) * (8.0f / 6.0f);
  float a = log2f(fabsf(v) + 1.0f) * (1.0f / 3.0f);
  return v < 0.0f ? -a : a;
}

// ---- fp32 -> bf16 conversion ----
__global__ __launch_bounds__(256) void cvt_bf16_kernel(
    const float* __restrict__ src, unsigned short* __restrict__ dst, int n8) {
  int i = blockIdx.x * 256 + threadIdx.x;
  if (i >= n8) return;
  const float* s = src + (size_t)i * 8;
  float4 a = *(const float4*)s;
  float4 b = *(const float4*)(s + 4);
  us8 o;
  o[0]=f2bf(a.x); o[1]=f2bf(a.y); o[2]=f2bf(a.z); o[3]=f2bf(a.w);
  o[4]=f2bf(b.x); o[5]=f2bf(b.y); o[6]=f2bf(b.z); o[7]=f2bf(b.w);
  *(us8*)(dst + (size_t)i * 8) = o;
}

// ---- gather x into window order + convert to bf16 ----
__global__ __launch_bounds__(256) void gather_x_kernel(
    const float* __restrict__ x, unsigned short* __restrict__ xg) {
  int chunk = blockIdx.x * 256 + threadIdx.x;
  if (chunk >= kM * 48) return;
  int wtok = chunk / 48, c = (chunk - wtok * 48) * 8;
  long row = winRowMap(wtok);
  const float* s = x + row * 384 + c;
  float4 a = *(const float4*)s;
  float4 b = *(const float4*)(s + 4);
  us8 o;
  o[0]=f2bf(a.x); o[1]=f2bf(a.y); o[2]=f2bf(a.z); o[3]=f2bf(a.w);
  o[4]=f2bf(b.x); o[5]=f2bf(b.y); o[6]=f2bf(b.z); o[7]=f2bf(b.w);
  *(us8*)(xg + (size_t)wtok * 384 + c) = o;
}

// ---- CPB MLP: tbl[2197][12] ----
__global__ __launch_bounds__(256) void cpb_table_kernel(
    const float* __restrict__ w1, const float* __restrict__ b1,
    const float* __restrict__ w2, float* __restrict__ tbl) {
  int t = blockIdx.x * 256 + threadIdx.x;
  if (t >= 2197 * 12) return;
  int row = t / 12, h = t - (t / 12) * 12;
  float f0 = cpbFeat(row / 169), f1 = cpbFeat((row / 13) % 13), f2 = cpbFeat(row % 13);
  float acc = 0.f;
  for (int j = 0; j < 512; ++j) {
    float hid = fmaf(f0, w1[j*3+0], fmaf(f1, w1[j*3+1], fmaf(f2, w1[j*3+2], b1[j])));
    hid = fmaxf(hid, 0.f);
    acc = fmaf(hid, w2[h*512 + j], acc);
  }
  tbl[row * 12 + h] = acc;
}

// ---- bias in swapped C-frag layout (row = k, col = q), pre-scaled by log2e ----
// biasf[h][qt][jt][lane][r]: i(query) = qt*16 + (lane&15), j(key) = jt*16 + (lane>>4)*4 + r
__global__ __launch_bounds__(256) void cpb_bias_frag_kernel(
    const float* __restrict__ tbl, float* __restrict__ biasf) {
  int gid = blockIdx.x * 256 + threadIdx.x;
  if (gid >= 12 * 22 * 22 * 64) return;
  int lane = gid & 63, tile = gid >> 6;
  int jt = tile % 22, qt = (tile / 22) % 22, h = tile / 484;
  int i = qt * 16 + (lane & 15);
  int j0 = jt * 16 + ((lane >> 4) << 2);
  float v[4];
  #pragma unroll
  for (int r = 0; r < 4; ++r) {
    int j = j0 + r;
    float val = -43000.f;
    if (i < kN && j < kN) {
      int iz = i/49, ih = (i/7)%7, iw = i%7;
      int jz = j/49, jh = (j/7)%7, jw = j%7;
      int idx = (iz-jz+6)*169 + (ih-jh+6)*13 + (iw-jw+6);
      float tv = tbl[idx*12 + h];
      val = (16.f / (1.f + __expf(-tv))) * kL2E;
    }
    v[r] = val;
  }
  *(float4*)(biasf + ((size_t)tile << 8) + (lane << 2)) = make_float4(v[0], v[1], v[2], v[3]);
}

// ---- standalone q/k cosine-norm, in place on the bf16 planes ----
// q row = q/||q|| * exp(min(ls,ln100)) * log2e ; k row = k/||k||   (r3 math relocated)
__global__ __launch_bounds__(256) void qknorm_kernel(
    unsigned short* __restrict__ qp, unsigned short* __restrict__ kp,
    const float* __restrict__ ls) {
  int gid = blockIdx.x * 256 + threadIdx.x;
  if (gid >= 768 * kN) return;
  int wh = gid / kN, t = gid - (gid / kN) * kN;
  int h = wh % 12;
  unsigned short* qr = qp + (size_t)wh * kN * 32 + (size_t)t * 32;
  unsigned short* kr = kp + (size_t)wh * kN * 32 + (size_t)t * 32;
  us8 q[4], k[4];
  float qs = 0.f, ks = 0.f;
  #pragma unroll
  for (int c = 0; c < 4; ++c) {
    q[c] = *(const us8*)(qr + c * 8);
    k[c] = *(const us8*)(kr + c * 8);
    #pragma unroll
    for (int e = 0; e < 8; ++e) {
      float fq = bf2f(q[c][e]); qs = fmaf(fq, fq, qs);
      float fk = bf2f(k[c][e]); ks = fmaf(fk, fk, ks);
    }
  }
  float qm = rsqrtf(fmaxf(qs, 1e-24f)) * __expf(fminf(ls[h], 4.6051702f)) * kL2E;
  float km = rsqrtf(fmaxf(ks, 1e-24f));
  #pragma unroll
  for (int c = 0; c < 4; ++c) {
    us8 oq, ok;
    #pragma unroll
    for (int e = 0; e < 8; ++e) {
      oq[e] = f2bf(bf2f(q[c][e]) * qm);
      ok[e] = f2bf(bf2f(k[c][e]) * km);
    }
    *(us8*)(qr + c * 8) = oq;
    *(us8*)(kr + c * 8) = ok;
  }
}

// ---- bf16 MFMA GEMM: out[M][N] = A[M][K] @ W[N][K]^T, BM=128 BN=128 BK=32 ----
// (verbatim round-3 kernel)
template <int MODE>
__global__ __launch_bounds__(256) void gemm_bf16(
    const unsigned short* __restrict__ A, const unsigned short* __restrict__ W,
    const float* __restrict__ b0, const float* __restrict__ b1,
    void* __restrict__ outv, int K, int N) {
  __shared__ __align__(16) unsigned short As[2][128][32];
  __shared__ __align__(16) unsigned short Bs[2][128][32];
  const int tid = threadIdx.x, lane = tid & 63, wid = tid >> 6;
  const int wr = wid >> 1, wc = wid & 1;
  const int lq = lane & 15, gq = lane >> 4;
  const int m0 = blockIdx.y * 128, n0 = blockIdx.x * 128;

  const int r0 = tid >> 2, c0 = (tid & 3) << 3;
  const unsigned short* gA0 = A + (size_t)(m0 + r0) * K + c0;
  const unsigned short* gA1 = A + (size_t)(m0 + 64 + r0) * K + c0;
  const unsigned short* gB0 = W + (size_t)(n0 + r0) * K + c0;
  const unsigned short* gB1 = W + (size_t)(n0 + 64 + r0) * K + c0;

  f4v acc[4][4];
  const f4v zero4 = {0.f, 0.f, 0.f, 0.f};
  #pragma unroll
  for (int i = 0; i < 4; ++i)
    #pragma unroll
    for (int j = 0; j < 4; ++j) acc[i][j] = zero4;

  const int nk = K >> 5;
#define STAGE(buf, kt)                                         \
  gload16(gA0 + (kt) * 32, &As[buf][r0][c0]);                  \
  gload16(gA1 + (kt) * 32, &As[buf][64 + r0][c0]);             \
  gload16(gB0 + (kt) * 32, &Bs[buf][r0][c0]);                  \
  gload16(gB1 + (kt) * 32, &Bs[buf][64 + r0][c0]);

  STAGE(0, 0);
  __syncthreads();
  for (int kt = 0; kt < nk; ++kt) {
    int cur = kt & 1;
    if (kt + 1 < nk) { STAGE(cur ^ 1, kt + 1); }
    s8v af[4];
    #pragma unroll
    for (int mt = 0; mt < 4; ++mt)
      af[mt] = *(const s8v*)&As[cur][wr * 64 + mt * 16 + lq][gq * 8];
    #pragma unroll
    for (int nt = 0; nt < 4; ++nt) {
      s8v bfr = *(const s8v*)&Bs[cur][wc * 64 + nt * 16 + lq][gq * 8];
      #pragma unroll
      for (int mt = 0; mt < 4; ++mt)
        acc[mt][nt] = __builtin_amdgcn_mfma_f32_16x16x32_bf16(af[mt], bfr, acc[mt][nt], 0, 0, 0);
    }
    __syncthreads();
  }
#undef STAGE

  if (MODE == 0) {
    unsigned short* qkv = (unsigned short*)outv;
    #pragma unroll
    for (int nt = 0; nt < 4; ++nt) {
      int cg = n0 + wc * 64 + nt * 16 + lq;
      int which = cg / 384, rem = cg - which * 384;
      const float* bp = (which == 0) ? b0 : (which == 2 ? b1 : nullptr);
      float badd = bp ? bp[rem] : 0.f;
      unsigned short* plane = qkv + (size_t)which * kPlaneE;
      #pragma unroll
      for (int mt = 0; mt < 4; ++mt)
        #pragma unroll
        for (int r = 0; r < 4; ++r) {
          int mg = m0 + wr * 64 + mt * 16 + gq * 4 + r;
          if (mg < kM) {
            int w = mg / kN, nn = mg - (mg / kN) * kN;
            plane[((size_t)(w * 12 + (rem >> 5)) * kN + nn) * 32 + (rem & 31)] =
                f2bf(acc[mt][nt][r] + badd);
          }
        }
    }
  } else {
    #pragma unroll
    for (int nt = 0; nt < 4; ++nt) {
      int cg = n0 + wc * 64 + nt * 16 + lq;
      float badd = b0[cg];
      #pragma unroll
      for (int mt = 0; mt < 4; ++mt)
        #pragma unroll
        for (int r = 0; r < 4; ++r) {
          size_t mg = (size_t)(m0 + wr * 64 + mt * 16 + gq * 4 + r);
          float t = acc[mt][nt][r] + badd;
          if (MODE == 2) {
            t = 0.5f * t * (1.f + erff(t * 0.70710678118f));
            ((unsigned short*)outv)[mg * N + cg] = f2bf(t);
          } else {
            ((float*)outv)[mg * N + cg] = t;
          }
        }
    }
  }
}

// ---- fused window attention (round-3 kernel minus the norm prologue) ----
__global__ __launch_bounds__(512) void attn_mfma(
    const unsigned short* __restrict__ qp, const unsigned short* __restrict__ kp,
    const unsigned short* __restrict__ vp, const float* __restrict__ biasf,
    unsigned short* __restrict__ outb) {
  __shared__ __align__(16) unsigned short Ksh[352][40];
  __shared__ __align__(16) unsigned short Vt[32][364];
  __shared__ float cntS[352];

  const int bid = blockIdx.x;
  const int h = bid >> 6, w = bid & 63;   // head-major: 64 consecutive blocks share bias slice
  const int wh = w * 12 + h;
  const int nwi = w & 7;
  const int tid = threadIdx.x, lane = tid & 63, wid = tid >> 6;
  const int lq = lane & 15, gq = lane >> 4;
  const unsigned short* qb = qp + (size_t)wh * kN * 32;
  const unsigned short* kb = kp + (size_t)wh * kN * 32;
  const unsigned short* vb = vp + (size_t)wh * kN * 32;

  // stage K rows (zero pads 343..351); K already normalized by qknorm
  for (int idx = tid; idx < 1408; idx += 512) {
    int r = idx >> 2, c8 = (idx & 3) << 3;
    us8 v = {0, 0, 0, 0, 0, 0, 0, 0};
    if (r < kN) v = *(const us8*)(kb + r * 32 + c8);
    *(us8*)&Ksh[r][c8] = v;
  }
  // zero Vt pad cols
  for (int idx = tid; idx < 288; idx += 512)
    Vt[idx / 9][343 + (idx % 9)] = 0;
  // transpose V into Vt[32][364]
  for (int idx = tid; idx < 1372; idx += 512) {
    int r = idx >> 2, c8 = (idx & 3) << 3;
    us8 v = *(const us8*)(vb + r * 32 + c8);
    #pragma unroll
    for (int e = 0; e < 8; ++e) Vt[c8 + e][r] = v[e];
  }
  // region counts (pure ALU)
  if (tid < 352) {
    int t = tid;
    if (t < kN) {
      int jz = t / 49, jh = (t / 7) % 7, jw = t % 7;
      cntS[t] = (float)(regionOf(((nwi >> 2) & 1) * 7 + jz) * 9 +
                        regionOf(((nwi >> 1) & 1) * 7 + jh) * 3 +
                        regionOf(((nwi     ) & 1) * 7 + jw));
    } else {
      cntS[t] = 0.f;
    }
  }
  __syncthreads();

  const f4v zero4 = {0.f, 0.f, 0.f, 0.f};

  for (int qt = wid; qt < 22; qt += 8) {
    const int i0 = qt * 16;
    s8v qa = *(const s8v*)(qb + (size_t)(i0 + lq) * 32 + gq * 8);  // pre-normalized q
    float ci = cntS[i0 + lq];
    const float* bb = biasf + (((size_t)(h * 22 + qt) * 22) << 8) + (lane << 2);

    float l2[22][4];
    #pragma unroll
    for (int jt = 0; jt < 22; ++jt) {
      s8v kf = *(const s8v*)&Ksh[jt * 16 + lq][gq * 8];
      f4v s4 = __builtin_amdgcn_mfma_f32_16x16x32_bf16(kf, qa, zero4, 0, 0, 0);
      float bqa[4];
      *(float4*)bqa = *(const float4*)(bb + ((size_t)jt << 8));
      #pragma unroll
      for (int r = 0; r < 4; ++r) {
        float cj = cntS[jt * 16 + 4 * gq + r];
        l2[jt][r] = s4[r] + bqa[r] + ((cj != ci) ? -144.269504f : 0.f);
      }
    }
    // row softmax (lane owns a full row; combine with 3 partner lanes)
    float m = -3e38f;
    #pragma unroll
    for (int jt = 0; jt < 22; ++jt)
      m = fmaxf(m, fmaxf(fmaxf(l2[jt][0], l2[jt][1]), fmaxf(l2[jt][2], l2[jt][3])));
    m = fmaxf(m, __shfl_xor(m, 16));
    m = fmaxf(m, __shfl_xor(m, 32));
    float sum = 0.f;
    s4v pa[22];
    #pragma unroll
    for (int jt = 0; jt < 22; ++jt) {
      float p0 = fexp2(l2[jt][0] - m), p1 = fexp2(l2[jt][1] - m);
      float p2 = fexp2(l2[jt][2] - m), p3 = fexp2(l2[jt][3] - m);
      sum += (p0 + p1) + (p2 + p3);
      union { unsigned u[2]; s4v s; } pk;
      pk.u[0] = cvtpk(p0, p1);
      pk.u[1] = cvtpk(p2, p3);
      pa[jt] = pk.s;
    }
    sum += __shfl_xor(sum, 16);
    sum += __shfl_xor(sum, 32);
    float rinv = 1.f / sum;

    // PV: K=16 MFMA, P straight from registers, V from transposed LDS
    f4v o0 = zero4, o1 = zero4;
    #pragma unroll
    for (int jt = 0; jt < 22; ++jt) {
      s4v v0 = *(const s4v*)&Vt[lq][jt * 16 + 4 * gq];
      s4v v1 = *(const s4v*)&Vt[16 + lq][jt * 16 + 4 * gq];
      o0 = mfma16(pa[jt], v0, o0);
      o1 = mfma16(pa[jt], v1, o1);
    }
    asm volatile("s_nop 7\ns_nop 7" :::);  // MFMA->VALU hazard guard (asm fallback path)
    #pragma unroll
    for (int r = 0; r < 4; ++r) {
      int q = i0 + 4 * gq + r;
      float rv = __shfl(rinv, 4 * gq + r);
      if (q < kN) {
        size_t base = ((size_t)(w * kN + q)) * 384 + h * 32;
        outb[base + lq]      = f2bf(o0[r] * rv);
        outb[base + 16 + lq] = f2bf(o1[r] * rv);
      }
    }
  }
}

// ---- LayerNorm + residual, 4 rows/block (round-3 kernel, fp32 src) ----
template <int GATHER, int WBF>
__global__ __launch_bounds__(256) void ln_kernel(
    const float* __restrict__ src, const float* __restrict__ resid,
    const float* __restrict__ g, const float* __restrict__ b,
    float* __restrict__ out, unsigned short* __restrict__ outbf) {
  int row = blockIdx.x * 4 + (threadIdx.x >> 6), lane = threadIdx.x & 63;
  long dst = GATHER ? (long)winRowMap(row) : (long)row;
  float t[6];
  float sum = 0.f, sq = 0.f;
  #pragma unroll
  for (int i = 0; i < 6; ++i) {
    t[i] = src[(long)row * 384 + i * 64 + lane];
    sum += t[i];
    sq = fmaf(t[i], t[i], sq);
  }
  #pragma unroll
  for (int o = 32; o; o >>= 1) { sum += __shfl_xor(sum, o); sq += __shfl_xor(sq, o); }
  float mean = sum * (1.f / 384.f);
  float var = sq * (1.f / 384.f) - mean * mean;
  float rs = rsqrtf(var + 1e-5f);
  #pragma unroll
  for (int i = 0; i < 6; ++i) {
    int c = i * 64 + lane;
    float val = resid[dst * 384 + c] + (t[i] - mean) * rs * g[c] + b[c];
    out[dst * 384 + c] = val;
    if (WBF) outbf[dst * 384 + c] = f2bf(val);
  }
}

}  // namespace

extern "C" void kernel_launch(void* const* d_in, const int* in_sizes, int n_in,
                              void* d_out, int out_size, void* d_ws, size_t ws_size,
                              hipStream_t stream) {
  const float* x      = (const float*)d_in[0];
  const float* qkv_w  = (const float*)d_in[1];
  const float* q_bias = (const float*)d_in[2];
  const float* v_bias = (const float*)d_in[3];
  const float* lscale = (const float*)d_in[4];
  const float* cpb_w1 = (const float*)d_in[5];
  const float* cpb_b1 = (const float*)d_in[6];
  const float* cpb_w2 = (const float*)d_in[7];
  const float* proj_w = (const float*)d_in[8];
  const float* proj_b = (const float*)d_in[9];
  const float* n1g    = (const float*)d_in[10];
  const float* n1b    = (const float*)d_in[11];
  const float* n2g    = (const float*)d_in[12];
  const float* n2b    = (const float*)d_in[13];
  const float* fc1_w  = (const float*)d_in[14];
  const float* fc1_b  = (const float*)d_in[15];
  const float* fc2_w  = (const float*)d_in[16];
  const float* fc2_b  = (const float*)d_in[17];
  float* outp = (float*)d_out;
  char* wsb = (char*)d_ws;

  // workspace layout (bytes), total ~178.4 MB (round-3 layout verbatim)
  float*          biasf = (float*)(wsb + 0);                  //  5,947,392
  float*          tbl   = (float*)(wsb + 5947392);            //    105,456
  unsigned short* qkvp  = (unsigned short*)(wsb + 6052864);   // 50,577,408
  unsigned short* xg    = (unsigned short*)(wsb + 56630272);  // 16,908,288 (22016 rows)
  unsigned short* attno = (unsigned short*)(wsb + 73538560);  // 16,908,288
  unsigned short* wts   = (unsigned short*)(wsb + 90446848);  //  3,538,944
  float*          projt = (float*)(wsb + 93985792);           // 33,816,576
  float*          x1    = (float*)(wsb + 127802368);          // 33,718,272
  unsigned short* x1b   = (unsigned short*)(wsb + 161520640); // 16,908,288
  unsigned short* hbuf  = qkvp;   // fc1 out overlays qkvp+xg+attno head (dead by then)
  float*          h2    = projt;  // fc2 out overlays projt (dead after LN1)

  unsigned short* wq  = wts;
  unsigned short* wpj = wts + 442368;
  unsigned short* wf1 = wts + 589824;
  unsigned short* wf2 = wts + 1179648;

  cvt_bf16_kernel<<<216, 256, 0, stream>>>(qkv_w, wq, 55296);
  cvt_bf16_kernel<<<72,  256, 0, stream>>>(proj_w, wpj, 18432);
  cvt_bf16_kernel<<<288, 256, 0, stream>>>(fc1_w, wf1, 73728);
  cvt_bf16_kernel<<<288, 256, 0, stream>>>(fc2_w, wf2, 73728);
  gather_x_kernel<<<4116, 256, 0, stream>>>(x, xg);
  cpb_table_kernel<<<103, 256, 0, stream>>>(cpb_w1, cpb_b1, cpb_w2, tbl);
  cpb_bias_frag_kernel<<<1452, 256, 0, stream>>>(tbl, biasf);

  // qkv: [22016p,384] @ [1152,384]^T -> q/k/v planes bf16 (raw + bias)
  gemm_bf16<0><<<dim3(9, 172), 256, 0, stream>>>(xg, wq, q_bias, v_bias, qkvp, 384, 1152);

  // in-place cosine norm: q = q/||q|| * exp(min(ls,ln100)) * log2e ; k = k/||k||
  qknorm_kernel<<<1029, 256, 0, stream>>>(qkvp, qkvp + kPlaneE, lscale);

  attn_mfma<<<768, 512, 0, stream>>>(qkvp, qkvp + kPlaneE, qkvp + 2 * kPlaneE, biasf, attno);

  // proj: [22016p,384] @ [384,384]^T + b -> fp32
  gemm_bf16<1><<<dim3(3, 172), 256, 0, stream>>>(attno, wpj, proj_b, nullptr, projt, 384, 384);

  // x1 = x + LN(win_rev(proj)); also bf16 copy
  ln_kernel<1, 1><<<5488, 256, 0, stream>>>(projt, x, n1g, n1b, x1, x1b);

  // fc1 + gelu: [22016p,384] @ [1536,384]^T -> bf16
  gemm_bf16<2><<<dim3(12, 172), 256, 0, stream>>>(x1b, wf1, fc1_b, nullptr, hbuf, 384, 1536);

  // fc2: [22016p,1536] @ [384,1536]^T -> fp32
  gemm_bf16<1><<<dim3(3, 172), 256, 0, stream>>>(hbuf, wf2, fc2_b, nullptr, h2, 1536, 384);

  // out = x1 + LN(h2)
  ln_kernel<0, 0><<<5488, 256, 0, stream>>>(h2, x1, n2g, n2b, outp, nullptr);
}

// Round 7
// 368.849 us; speedup vs baseline: 1.1154x; 1.1154x over previous
//
#include <hip/hip_runtime.h>
#include <hip/hip_bf16.h>
#include <stdint.h>

namespace {

typedef __attribute__((ext_vector_type(8))) short s8v;
typedef __attribute__((ext_vector_type(4))) short s4v;
typedef __attribute__((ext_vector_type(4))) float f4v;
typedef __attribute__((ext_vector_type(8))) unsigned short us8;

constexpr int kN = 343;                        // window tokens (7^3)
constexpr size_t kPlaneE = 768ull * 343 * 32;  // elems per q/k/v plane
constexpr int kM = 21952;                      // real rows
constexpr float kL2E = 1.44269504f;

__device__ __forceinline__ int regionOf(int c) { return c < 7 ? 0 : (c < 11 ? 1 : 2); }

__device__ __forceinline__ int winRowMap(int wtok) {
  int w = wtok / kN, nn = wtok % kN;
  int bb = w >> 3, nwi = w & 7;
  int nz = nn / 49, nh = (nn / 7) % 7, nw = nn % 7;
  int uz = (((nwi >> 2) & 1) * 7 + nz + 3) % 14;
  int uh = (((nwi >> 1) & 1) * 7 + nh + 3) % 14;
  int uw = (((nwi     ) & 1) * 7 + nw + 3) % 14;
  return bb * 2744 + uz * 196 + uh * 14 + uw;
}

__device__ __forceinline__ unsigned short f2bf(float f) {
  union { float f; unsigned u; } a; a.f = f;
  unsigned r = a.u + 0x7fffu + ((a.u >> 16) & 1u);
  return (unsigned short)(r >> 16);
}
__device__ __forceinline__ float bf2f(unsigned short u) {
  union { unsigned u; float f; } a; a.u = ((unsigned)u) << 16; return a.f;
}
__device__ __forceinline__ unsigned cvtpk(float lo, float hi) {
  unsigned r;
  asm("v_cvt_pk_bf16_f32 %0, %1, %2" : "=v"(r) : "v"(lo), "v"(hi));
  return r;
}
__device__ __forceinline__ float fexp2(float x) {
#if __has_builtin(__builtin_amdgcn_exp2f)
  return __builtin_amdgcn_exp2f(x);
#else
  return exp2f(x);
#endif
}

#if __has_builtin(__builtin_amdgcn_mfma_f32_16x16x16bf16_1k)
__device__ __forceinline__ f4v mfma16(s4v a, s4v b, f4v c) {
  return __builtin_amdgcn_mfma_f32_16x16x16bf16_1k(a, b, c, 0, 0, 0);
}
#else
__device__ __forceinline__ f4v mfma16(s4v a, s4v b, f4v c) {
  f4v d;
  asm("v_mfma_f32_16x16x16_bf16 %0, %1, %2, %3" : "=v"(d) : "v"(a), "v"(b), "v"(c));
  return d;
}
#endif

__device__ __forceinline__ void gload16(const void* g, void* l) {
  __builtin_amdgcn_global_load_lds(
      (const __attribute__((address_space(1))) unsigned int*)g,
      (__attribute__((address_space(3))) unsigned int*)l, 16, 0, 0);
}

__device__ __forceinline__ float cpbFeat(int i) {
  float v = (float)(i - 6) * (8.0f / 6.0f);
  float a = log2f(fabsf(v) + 1.0f) * (1.0f / 3.0f);
  return v < 0.0f ? -a : a;
}

// bijective 8-way XCD chunk swizzle (m204)
__device__ __forceinline__ int xcdSwz(int bid, int nwg) {
  int q = nwg >> 3, r = nwg & 7;
  int x = bid & 7, p = bid >> 3;
  return (x < r ? x * (q + 1) : r * (q + 1) + (x - r) * q) + p;
}

// ---- all weight fp32 -> bf16 conversions in one kernel ----
__global__ __launch_bounds__(256) void cvt_all_kernel(
    const float* __restrict__ qkv_w, const float* __restrict__ proj_w,
    const float* __restrict__ fc1_w, const float* __restrict__ fc2_w,
    unsigned short* __restrict__ wts) {
  int i = blockIdx.x * 256 + threadIdx.x;
  if (i >= 221184) return;
  const float* src; size_t dstoff; int rel;
  if (i < 55296)       { src = qkv_w;  rel = i;          dstoff = 0; }
  else if (i < 73728)  { src = proj_w; rel = i - 55296;  dstoff = 442368; }
  else if (i < 147456) { src = fc1_w;  rel = i - 73728;  dstoff = 589824; }
  else                 { src = fc2_w;  rel = i - 147456; dstoff = 1179648; }
  const float* s = src + (size_t)rel * 8;
  float4 a = *(const float4*)s;
  float4 b = *(const float4*)(s + 4);
  us8 o;
  o[0]=f2bf(a.x); o[1]=f2bf(a.y); o[2]=f2bf(a.z); o[3]=f2bf(a.w);
  o[4]=f2bf(b.x); o[5]=f2bf(b.y); o[6]=f2bf(b.z); o[7]=f2bf(b.w);
  *(us8*)(wts + dstoff + (size_t)rel * 8) = o;
}

// ---- gather x into window order + convert to bf16 ----
__global__ __launch_bounds__(256) void gather_x_kernel(
    const float* __restrict__ x, unsigned short* __restrict__ xg) {
  int chunk = blockIdx.x * 256 + threadIdx.x;
  if (chunk >= kM * 48) return;
  int wtok = chunk / 48, c = (chunk - wtok * 48) * 8;
  long row = winRowMap(wtok);
  const float* s = x + row * 384 + c;
  float4 a = *(const float4*)s;
  float4 b = *(const float4*)(s + 4);
  us8 o;
  o[0]=f2bf(a.x); o[1]=f2bf(a.y); o[2]=f2bf(a.z); o[3]=f2bf(a.w);
  o[4]=f2bf(b.x); o[5]=f2bf(b.y); o[6]=f2bf(b.z); o[7]=f2bf(b.w);
  *(us8*)(xg + (size_t)wtok * 384 + c) = o;
}

// ---- CPB MLP: tbl[2197][12] ----
__global__ __launch_bounds__(256) void cpb_table_kernel(
    const float* __restrict__ w1, const float* __restrict__ b1,
    const float* __restrict__ w2, float* __restrict__ tbl) {
  int t = blockIdx.x * 256 + threadIdx.x;
  if (t >= 2197 * 12) return;
  int row = t / 12, h = t - (t / 12) * 12;
  float f0 = cpbFeat(row / 169), f1 = cpbFeat((row / 13) % 13), f2 = cpbFeat(row % 13);
  float acc = 0.f;
  for (int j = 0; j < 512; ++j) {
    float hid = fmaf(f0, w1[j*3+0], fmaf(f1, w1[j*3+1], fmaf(f2, w1[j*3+2], b1[j])));
    hid = fmaxf(hid, 0.f);
    acc = fmaf(hid, w2[h*512 + j], acc);
  }
  tbl[row * 12 + h] = acc;
}

// ---- bias in swapped C-frag layout (row = k, col = q), pre-scaled by log2e ----
__global__ __launch_bounds__(256) void cpb_bias_frag_kernel(
    const float* __restrict__ tbl, float* __restrict__ biasf) {
  int gid = blockIdx.x * 256 + threadIdx.x;
  if (gid >= 12 * 22 * 22 * 64) return;
  int lane = gid & 63, tile = gid >> 6;
  int jt = tile % 22, qt = (tile / 22) % 22, h = tile / 484;
  int i = qt * 16 + (lane & 15);
  int j0 = jt * 16 + ((lane >> 4) << 2);
  float v[4];
  #pragma unroll
  for (int r = 0; r < 4; ++r) {
    int j = j0 + r;
    float val = -43000.f;
    if (i < kN && j < kN) {
      int iz = i/49, ih = (i/7)%7, iw = i%7;
      int jz = j/49, jh = (j/7)%7, jw = j%7;
      int idx = (iz-jz+6)*169 + (ih-jh+6)*13 + (iw-jw+6);
      float tv = tbl[idx*12 + h];
      val = (16.f / (1.f + __expf(-tv))) * kL2E;
    }
    v[r] = val;
  }
  *(float4*)(biasf + ((size_t)tile << 8) + (lane << 2)) = make_float4(v[0], v[1], v[2], v[3]);
}

// ---- standalone q/k cosine-norm, in place on the bf16 planes ----
__global__ __launch_bounds__(256) void qknorm_kernel(
    unsigned short* __restrict__ qp, unsigned short* __restrict__ kp,
    const float* __restrict__ ls) {
  int gid = blockIdx.x * 256 + threadIdx.x;
  if (gid >= 768 * kN) return;
  int wh = gid / kN, t = gid - (gid / kN) * kN;
  int h = wh % 12;
  unsigned short* qr = qp + (size_t)wh * kN * 32 + (size_t)t * 32;
  unsigned short* kr = kp + (size_t)wh * kN * 32 + (size_t)t * 32;
  us8 q[4], k[4];
  float qs = 0.f, ks = 0.f;
  #pragma unroll
  for (int c = 0; c < 4; ++c) {
    q[c] = *(const us8*)(qr + c * 8);
    k[c] = *(const us8*)(kr + c * 8);
    #pragma unroll
    for (int e = 0; e < 8; ++e) {
      float fq = bf2f(q[c][e]); qs = fmaf(fq, fq, qs);
      float fk = bf2f(k[c][e]); ks = fmaf(fk, fk, ks);
    }
  }
  float qm = rsqrtf(fmaxf(qs, 1e-24f)) * __expf(fminf(ls[h], 4.6051702f)) * kL2E;
  float km = rsqrtf(fmaxf(ks, 1e-24f));
  #pragma unroll
  for (int c = 0; c < 4; ++c) {
    us8 oq, ok;
    #pragma unroll
    for (int e = 0; e < 8; ++e) {
      oq[e] = f2bf(bf2f(q[c][e]) * qm);
      ok[e] = f2bf(bf2f(k[c][e]) * km);
    }
    *(us8*)(qr + c * 8) = oq;
    *(us8*)(kr + c * 8) = ok;
  }
}

// ---- bf16 MFMA GEMM: out[M][N] = A[M][K] @ W[N][K]^T, BM=128 BN=128 BK=32 ----
// XCD-swizzled grid. All outputs bf16.
// MODE 0: qkv scatter to planes (+q/v bias). MODE 1: +bias. MODE 2: +bias, GELU.
template <int MODE>
__global__ __launch_bounds__(256) void gemm_bf16(
    const unsigned short* __restrict__ A, const unsigned short* __restrict__ W,
    const float* __restrict__ b0, const float* __restrict__ b1,
    unsigned short* __restrict__ outv, int K, int N, int nbx) {
  __shared__ __align__(16) unsigned short As[2][128][32];
  __shared__ __align__(16) unsigned short Bs[2][128][32];
  const int wg = xcdSwz(blockIdx.x, gridDim.x);
  const int by = wg / nbx, bx = wg - by * nbx;
  const int m0 = by * 128, n0 = bx * 128;
  const int tid = threadIdx.x, lane = tid & 63, wid = tid >> 6;
  const int wr = wid >> 1, wc = wid & 1;
  const int lq = lane & 15, gq = lane >> 4;

  const int r0 = tid >> 2, c0 = (tid & 3) << 3;
  const unsigned short* gA0 = A + (size_t)(m0 + r0) * K + c0;
  const unsigned short* gA1 = A + (size_t)(m0 + 64 + r0) * K + c0;
  const unsigned short* gB0 = W + (size_t)(n0 + r0) * K + c0;
  const unsigned short* gB1 = W + (size_t)(n0 + 64 + r0) * K + c0;

  f4v acc[4][4];
  const f4v zero4 = {0.f, 0.f, 0.f, 0.f};
  #pragma unroll
  for (int i = 0; i < 4; ++i)
    #pragma unroll
    for (int j = 0; j < 4; ++j) acc[i][j] = zero4;

  const int nk = K >> 5;
#define STAGE(buf, kt)                                         \
  gload16(gA0 + (kt) * 32, &As[buf][r0][c0]);                  \
  gload16(gA1 + (kt) * 32, &As[buf][64 + r0][c0]);             \
  gload16(gB0 + (kt) * 32, &Bs[buf][r0][c0]);                  \
  gload16(gB1 + (kt) * 32, &Bs[buf][64 + r0][c0]);

  STAGE(0, 0);
  __syncthreads();
  for (int kt = 0; kt < nk; ++kt) {
    int cur = kt & 1;
    if (kt + 1 < nk) { STAGE(cur ^ 1, kt + 1); }
    s8v af[4];
    #pragma unroll
    for (int mt = 0; mt < 4; ++mt)
      af[mt] = *(const s8v*)&As[cur][wr * 64 + mt * 16 + lq][gq * 8];
    #pragma unroll
    for (int nt = 0; nt < 4; ++nt) {
      s8v bfr = *(const s8v*)&Bs[cur][wc * 64 + nt * 16 + lq][gq * 8];
      #pragma unroll
      for (int mt = 0; mt < 4; ++mt)
        acc[mt][nt] = __builtin_amdgcn_mfma_f32_16x16x32_bf16(af[mt], bfr, acc[mt][nt], 0, 0, 0);
    }
    __syncthreads();
  }
#undef STAGE

  if (MODE == 0) {
    #pragma unroll
    for (int nt = 0; nt < 4; ++nt) {
      int cg = n0 + wc * 64 + nt * 16 + lq;
      int which = cg / 384, rem = cg - which * 384;
      const float* bp = (which == 0) ? b0 : (which == 2 ? b1 : nullptr);
      float badd = bp ? bp[rem] : 0.f;
      unsigned short* plane = outv + (size_t)which * kPlaneE;
      #pragma unroll
      for (int mt = 0; mt < 4; ++mt)
        #pragma unroll
        for (int r = 0; r < 4; ++r) {
          int mg = m0 + wr * 64 + mt * 16 + gq * 4 + r;
          if (mg < kM) {
            int w = mg / kN, nn = mg - (mg / kN) * kN;
            plane[((size_t)(w * 12 + (rem >> 5)) * kN + nn) * 32 + (rem & 31)] =
                f2bf(acc[mt][nt][r] + badd);
          }
        }
    }
  } else {
    #pragma unroll
    for (int nt = 0; nt < 4; ++nt) {
      int cg = n0 + wc * 64 + nt * 16 + lq;
      float badd = b0[cg];
      #pragma unroll
      for (int mt = 0; mt < 4; ++mt)
        #pragma unroll
        for (int r = 0; r < 4; ++r) {
          size_t mg = (size_t)(m0 + wr * 64 + mt * 16 + gq * 4 + r);
          float t = acc[mt][nt][r] + badd;
          if (MODE == 2) t = 0.5f * t * (1.f + erff(t * 0.70710678118f));
          outv[mg * N + cg] = f2bf(t);
        }
    }
  }
}

// ---- fused window attention (verbatim round-6, no swizzle) ----
__global__ __launch_bounds__(512) void attn_mfma(
    const unsigned short* __restrict__ qp, const unsigned short* __restrict__ kp,
    const unsigned short* __restrict__ vp, const float* __restrict__ biasf,
    unsigned short* __restrict__ outb) {
  __shared__ __align__(16) unsigned short Ksh[352][40];
  __shared__ __align__(16) unsigned short Vt[32][364];
  __shared__ float cntS[352];

  const int bid = blockIdx.x;
  const int h = bid >> 6, w = bid & 63;
  const int wh = w * 12 + h;
  const int nwi = w & 7;
  const int tid = threadIdx.x, lane = tid & 63, wid = tid >> 6;
  const int lq = lane & 15, gq = lane >> 4;
  const unsigned short* qb = qp + (size_t)wh * kN * 32;
  const unsigned short* kb = kp + (size_t)wh * kN * 32;
  const unsigned short* vb = vp + (size_t)wh * kN * 32;

  for (int idx = tid; idx < 1408; idx += 512) {
    int r = idx >> 2, c8 = (idx & 3) << 3;
    us8 v = {0, 0, 0, 0, 0, 0, 0, 0};
    if (r < kN) v = *(const us8*)(kb + r * 32 + c8);
    *(us8*)&Ksh[r][c8] = v;
  }
  for (int idx = tid; idx < 288; idx += 512)
    Vt[idx / 9][343 + (idx % 9)] = 0;
  for (int idx = tid; idx < 1372; idx += 512) {
    int r = idx >> 2, c8 = (idx & 3) << 3;
    us8 v = *(const us8*)(vb + r * 32 + c8);
    #pragma unroll
    for (int e = 0; e < 8; ++e) Vt[c8 + e][r] = v[e];
  }
  if (tid < 352) {
    int t = tid;
    if (t < kN) {
      int jz = t / 49, jh = (t / 7) % 7, jw = t % 7;
      cntS[t] = (float)(regionOf(((nwi >> 2) & 1) * 7 + jz) * 9 +
                        regionOf(((nwi >> 1) & 1) * 7 + jh) * 3 +
                        regionOf(((nwi     ) & 1) * 7 + jw));
    } else {
      cntS[t] = 0.f;
    }
  }
  __syncthreads();

  const f4v zero4 = {0.f, 0.f, 0.f, 0.f};

  for (int qt = wid; qt < 22; qt += 8) {
    const int i0 = qt * 16;
    s8v qa = *(const s8v*)(qb + (size_t)(i0 + lq) * 32 + gq * 8);
    float ci = cntS[i0 + lq];
    const float* bb = biasf + (((size_t)(h * 22 + qt) * 22) << 8) + (lane << 2);

    float l2[22][4];
    #pragma unroll
    for (int jt = 0; jt < 22; ++jt) {
      s8v kf = *(const s8v*)&Ksh[jt * 16 + lq][gq * 8];
      f4v s4 = __builtin_amdgcn_mfma_f32_16x16x32_bf16(kf, qa, zero4, 0, 0, 0);
      float bqa[4];
      *(float4*)bqa = *(const float4*)(bb + ((size_t)jt << 8));
      #pragma unroll
      for (int r = 0; r < 4; ++r) {
        float cj = cntS[jt * 16 + 4 * gq + r];
        l2[jt][r] = s4[r] + bqa[r] + ((cj != ci) ? -144.269504f : 0.f);
      }
    }
    float m = -3e38f;
    #pragma unroll
    for (int jt = 0; jt < 22; ++jt)
      m = fmaxf(m, fmaxf(fmaxf(l2[jt][0], l2[jt][1]), fmaxf(l2[jt][2], l2[jt][3])));
    m = fmaxf(m, __shfl_xor(m, 16));
    m = fmaxf(m, __shfl_xor(m, 32));
    float sum = 0.f;
    s4v pa[22];
    #pragma unroll
    for (int jt = 0; jt < 22; ++jt) {
      float p0 = fexp2(l2[jt][0] - m), p1 = fexp2(l2[jt][1] - m);
      float p2 = fexp2(l2[jt][2] - m), p3 = fexp2(l2[jt][3] - m);
      sum += (p0 + p1) + (p2 + p3);
      union { unsigned u[2]; s4v s; } pk;
      pk.u[0] = cvtpk(p0, p1);
      pk.u[1] = cvtpk(p2, p3);
      pa[jt] = pk.s;
    }
    sum += __shfl_xor(sum, 16);
    sum += __shfl_xor(sum, 32);
    float rinv = 1.f / sum;

    f4v o0 = zero4, o1 = zero4;
    #pragma unroll
    for (int jt = 0; jt < 22; ++jt) {
      s4v v0 = *(const s4v*)&Vt[lq][jt * 16 + 4 * gq];
      s4v v1 = *(const s4v*)&Vt[16 + lq][jt * 16 + 4 * gq];
      o0 = mfma16(pa[jt], v0, o0);
      o1 = mfma16(pa[jt], v1, o1);
    }
    asm volatile("s_nop 7\ns_nop 7" :::);
    #pragma unroll
    for (int r = 0; r < 4; ++r) {
      int q = i0 + 4 * gq + r;
      float rv = __shfl(rinv, 4 * gq + r);
      if (q < kN) {
        size_t base = ((size_t)(w * kN + q)) * 384 + h * 32;
        outb[base + lq]      = f2bf(o0[r] * rv);
        outb[base + 16 + lq] = f2bf(o1[r] * rv);
      }
    }
  }
}

// ---- LayerNorm + residual, bf16 src, 4 rows/block ----
// RB: resid dtype bf16(1)/fp32(0); OB: output bf16(1)/fp32(0)
template <int GATHER, int RB, int OB>
__global__ __launch_bounds__(256) void ln_kernel(
    const unsigned short* __restrict__ src, const void* __restrict__ residv,
    const float* __restrict__ g, const float* __restrict__ b,
    float* __restrict__ outf, unsigned short* __restrict__ outb) {
  int row = blockIdx.x * 4 + (threadIdx.x >> 6), lane = threadIdx.x & 63;
  long dst = GATHER ? (long)winRowMap(row) : (long)row;
  float t[6];
  float sum = 0.f, sq = 0.f;
  #pragma unroll
  for (int i = 0; i < 6; ++i) {
    t[i] = bf2f(src[(long)row * 384 + i * 64 + lane]);
    sum += t[i];
    sq = fmaf(t[i], t[i], sq);
  }
  #pragma unroll
  for (int o = 32; o; o >>= 1) { sum += __shfl_xor(sum, o); sq += __shfl_xor(sq, o); }
  float mean = sum * (1.f / 384.f);
  float var = sq * (1.f / 384.f) - mean * mean;
  float rs = rsqrtf(var + 1e-5f);
  #pragma unroll
  for (int i = 0; i < 6; ++i) {
    int c = i * 64 + lane;
    float rv = RB ? bf2f(((const unsigned short*)residv)[dst * 384 + c])
                  : ((const float*)residv)[dst * 384 + c];
    float val = rv + (t[i] - mean) * rs * g[c] + b[c];
    if (OB) outb[dst * 384 + c] = f2bf(val);
    else    outf[dst * 384 + c] = val;
  }
}

}  // namespace

extern "C" void kernel_launch(void* const* d_in, const int* in_sizes, int n_in,
                              void* d_out, int out_size, void* d_ws, size_t ws_size,
                              hipStream_t stream) {
  const float* x      = (const float*)d_in[0];
  const float* qkv_w  = (const float*)d_in[1];
  const float* q_bias = (const float*)d_in[2];
  const float* v_bias = (const float*)d_in[3];
  const float* lscale = (const float*)d_in[4];
  const float* cpb_w1 = (const float*)d_in[5];
  const float* cpb_b1 = (const float*)d_in[6];
  const float* cpb_w2 = (const float*)d_in[7];
  const float* proj_w = (const float*)d_in[8];
  const float* proj_b = (const float*)d_in[9];
  const float* n1g    = (const float*)d_in[10];
  const float* n1b    = (const float*)d_in[11];
  const float* n2g    = (const float*)d_in[12];
  const float* n2b    = (const float*)d_in[13];
  const float* fc1_w  = (const float*)d_in[14];
  const float* fc1_b  = (const float*)d_in[15];
  const float* fc2_w  = (const float*)d_in[16];
  const float* fc2_b  = (const float*)d_in[17];
  float* outp = (float*)d_out;
  char* wsb = (char*)d_ws;

  // workspace layout (bytes), total ~128 MB
  float*          biasf = (float*)(wsb + 0);                  //  5,947,392
  float*          tbl   = (float*)(wsb + 5947392);            //    105,456
  unsigned short* qkvp  = (unsigned short*)(wsb + 6052864);   // 50,577,408
  unsigned short* xg    = (unsigned short*)(wsb + 56630272);  // 16,908,288 (22016 rows)
  unsigned short* attno = (unsigned short*)(wsb + 73538560);  // 16,908,288
  unsigned short* wts   = (unsigned short*)(wsb + 90446848);  //  3,538,944
  unsigned short* projt = (unsigned short*)(wsb + 93985792);  // 16,908,288
  unsigned short* x1b   = (unsigned short*)(wsb + 110894080); // 16,908,288
  unsigned short* hbuf  = qkvp;    // fc1 out (67.6MB) overlays qkvp+xg (+attno head, dead)
  unsigned short* h2    = projt;   // fc2 out overlays projt (dead after LN1)

  unsigned short* wq  = wts;
  unsigned short* wpj = wts + 442368;
  unsigned short* wf1 = wts + 589824;
  unsigned short* wf2 = wts + 1179648;

  cvt_all_kernel<<<864, 256, 0, stream>>>(qkv_w, proj_w, fc1_w, fc2_w, wts);
  gather_x_kernel<<<4116, 256, 0, stream>>>(x, xg);
  cpb_table_kernel<<<103, 256, 0, stream>>>(cpb_w1, cpb_b1, cpb_w2, tbl);
  cpb_bias_frag_kernel<<<1452, 256, 0, stream>>>(tbl, biasf);

  // qkv: [22016p,384] @ [1152,384]^T -> q/k/v planes bf16 (raw + bias)
  gemm_bf16<0><<<1548, 256, 0, stream>>>(xg, wq, q_bias, v_bias, qkvp, 384, 1152, 9);

  // in-place cosine norm: q = q/||q|| * exp(min(ls,ln100)) * log2e ; k = k/||k||
  qknorm_kernel<<<1029, 256, 0, stream>>>(qkvp, qkvp + kPlaneE, lscale);

  attn_mfma<<<768, 512, 0, stream>>>(qkvp, qkvp + kPlaneE, qkvp + 2 * kPlaneE, biasf, attno);

  // proj: [22016p,384] @ [384,384]^T + b -> bf16
  gemm_bf16<1><<<516, 256, 0, stream>>>(attno, wpj, proj_b, nullptr, projt, 384, 384, 3);

  // x1 = x + LN(win_rev(proj)) -> bf16 only
  ln_kernel<1, 0, 1><<<5488, 256, 0, stream>>>(projt, x, n1g, n1b, nullptr, x1b);

  // fc1 + gelu: [22016p,384] @ [1536,384]^T -> bf16
  gemm_bf16<2><<<2064, 256, 0, stream>>>(x1b, wf1, fc1_b, nullptr, hbuf, 384, 1536, 12);

  // fc2: [22016p,1536] @ [384,1536]^T -> bf16
  gemm_bf16<1><<<516, 256, 0, stream>>>(hbuf, wf2, fc2_b, nullptr, h2, 1536, 384, 3);

  // out = x1 + LN(h2), fp32 out
  ln_kernel<0, 1, 0><<<5488, 256, 0, stream>>>(h2, x1b, n2g, n2b, outp, nullptr);
}